// Round 7
// baseline (1819.666 us; speedup 1.0000x reference)
//
#include <hip/hip_runtime.h>
#include <math.h>

// Problem constants (match reference)
#define BB 256
#define TT 512
#define SS 64
#define OO 128
#define HH 128
#define FH 512  // 4*H
#define CH 16   // time-chunk

#define LOG2PI_F 1.8378770664093453f

// ws layout (bytes): [acc: 8B][pad][qpm: B*T*S*4 = 32MB]
#define ACC_OFF 0
#define QPM_OFF 256

__device__ __forceinline__ float softplusf(float x) {
    // matches jax.nn.softplus: max(x,0) + log1p(exp(-|x|))
    return fmaxf(x, 0.f) + log1pf(expf(-fabsf(x)));
}
__device__ __forceinline__ float sigmoidf(float x) {
    return 1.f / (1.f + expf(-x));
}

__global__ void zero_acc_kernel(double* acc) { acc[0] = 0.0; }
__global__ void finalize_kernel(const double* acc, float* out) { out[0] = (float)acc[0]; }

// ---------------------------------------------------------------------------
// Fused kernel: one block per batch (256 blocks x 1024 threads = 16 waves).
// REGISTER-BUDGET NOTE (R5/R6 post-mortem): with LDS=73KB two blocks fit per
// CU, so the backend targeted 8 waves/EU -> 64-VGPR budget -> ~26 floats of
// loop-invariant weights spilled to scratch (28MB WRITE_SIZE, VALUBusy 54%).
// Grid=256 blocks on 256 CUs means a 2nd block/CU never exists. Fix: pad LDS
// past 80KB (wred[3000]) so 1 block/CU is the only option -> 4 waves/EU ->
// 128-VGPR budget -> rc[64]+az[8]+misc (~110) fits with no spill.
//  step loop (2 barriers/step), only true recurrences:
//    P1: z-partials (rc[64], 2-way k-split over 1024 threads -> Pz[2][512])
//        + prior-mean partials (threads 768.., wf[16], 4-way split -> Pf)
//    P2: t<128: gate math + h update; t in[128,192): prior-mean combine
//  chunk phase (parallel, per 16 steps): obs@K az-GEMM (pre-staged),
//    Wr heads + prior-scale (from m_{t-1} archive) + KL, weights from L2.
// ---------------------------------------------------------------------------
__global__ __launch_bounds__(1024) __attribute__((amdgpu_waves_per_eu(4, 4)))
void kFused(
    const float* __restrict__ obs, const float* __restrict__ K,
    const float* __restrict__ bl,  const float* __restrict__ Rw,
    const float* __restrict__ Wfm, const float* __restrict__ bfm,
    const float* __restrict__ Wfs, const float* __restrict__ bfs,
    const float* __restrict__ im,
    const float* __restrict__ Wrm, const float* __restrict__ brm,
    const float* __restrict__ Wrs, const float* __restrict__ brs,
    float* __restrict__ qpm, double* __restrict__ acc_out)
{
    __shared__ float sobs[CH * 128];    // obs chunk, natural [s][k]      8.0 KB
    __shared__ float azs[CH * 512];     // obs@K for chunk [s][col]      32.0 KB
    __shared__ float hch[CH * 132];     // h archive [s][k] (pad 4)       8.4 KB
    __shared__ float qch[CH * 132];     // head out: qm | sp              8.4 KB
    __shared__ float prmch[CH * 68];    // prior mean archive             4.3 KB
    __shared__ float sqch[CH * 68];     // prior scale                    4.3 KB
    __shared__ float Pz[2 * 516];       // z partials (2-way k-split)     4.1 KB
    __shared__ float Pf[4 * 68];        // prior-mean partials            1.1 KB
    __shared__ float h_lds[128];
    __shared__ float m_lds[64];
    __shared__ float m0ch[64];          // m at chunk start
    __shared__ float wred[3000];        // [0..15] used; rest = LDS pad that
                                        // forces 1 block/CU (see note above)

    const int t = threadIdx.x;
    const int b = blockIdx.x;

    // ---- z-matvec ownership: col zc, k-half kh ----
    const int zc = t & 511;
    const int kh = t >> 9;  // 0 or 1
    float rc[64];
#pragma unroll
    for (int kk = 0; kk < 64; ++kk) rc[kk] = Rw[(kh * 64 + kk) * 512 + zc];

    // ---- prior-mean partial ownership (threads 768..1023) ----
    const int pc = t & 63;
    const int pq = (t >> 6) & 3;
    float wf[16];
    if (t >= 768) {
#pragma unroll
        for (int kk = 0; kk < 16; ++kk) wf[kk] = Wfm[(pq * 16 + kk) * 64 + pc];
    }

    // ---- role constants ----
    float bl0 = 0.f, bl1 = 0.f, bl2 = 0.f, bl3 = 0.f, cst = 0.f, bfmr = 0.f;
    if (t < 128) { bl0 = bl[t]; bl1 = bl[t + 128]; bl2 = bl[t + 256]; bl3 = bl[t + 384]; }
    else if (t < 192) bfmr = bfm[t - 128];

    // ---- head job constants: cols hc for steps hs2 and hs2+8 ----
    const int hc  = t & 127;
    const int hs2 = t >> 7;  // 0..7
    const float* Wcol = (hc < 64) ? (Wrm + hc) : (Wrs + (hc - 64));
    const float hbias = (hc < 64) ? brm[hc] : brs[hc - 64];
    // ---- prior-scale / KL job constants: (step ss, col pc) ----
    const int ss = t >> 6;   // 0..15
    const float bfsr = bfs[pc];

    float acckl = 0.f;
    if (t < 128) h_lds[t] = 0.f;
    if (t < 64)  m_lds[t] = im[b * 64 + t];
    __syncthreads();

    const float* obsb = obs + (size_t)b * TT * OO;
    float* qrow = qpm + (size_t)b * TT * SS;

    for (int t0 = 0; t0 < TT; t0 += CH) {
        // ---- stage obs chunk + m at chunk start ----
        if (t < 512) ((float4*)sobs)[t] = ((const float4*)(obsb + (size_t)t0 * OO))[t];
        if (t < 64) m0ch[t] = m_lds[t];
        __syncthreads();  // A: sobs/m0ch ready

        // ---- az chunk GEMM: thread (zc, kh) -> steps kh*8..kh*8+7, col zc ----
        {
            float az[8];
#pragma unroll
            for (int j = 0; j < 8; ++j) az[j] = 0.f;
            const float* srow = sobs + (kh * 8) * 128;
            for (int kb = 0; kb < 32; ++kb) {
                const float k0 = K[(4 * kb + 0) * 512 + zc];
                const float k1 = K[(4 * kb + 1) * 512 + zc];
                const float k2 = K[(4 * kb + 2) * 512 + zc];
                const float k3 = K[(4 * kb + 3) * 512 + zc];
#pragma unroll
                for (int j = 0; j < 8; ++j) {
                    const float4 o = *(const float4*)&srow[j * 128 + 4 * kb];
                    az[j] += o.x * k0 + o.y * k1 + o.z * k2 + o.w * k3;
                }
            }
#pragma unroll
            for (int j = 0; j < 8; ++j) azs[(kh * 8 + j) * 512 + zc] = az[j];
            // azs reads are protected by B1 of step 0
        }

        // ---- 16 sequential steps, 2 barriers each ----
#pragma unroll 1
        for (int si = 0; si < CH; ++si) {
            // P1: z partial for (zc, kh)
            {
                const float4* h4 = (const float4*)&h_lds[kh * 64];
                float a0 = 0.f, a1 = 0.f, a2 = 0.f, a3 = 0.f;
#pragma unroll
                for (int kb = 0; kb < 16; ++kb) {
                    const float4 v = h4[kb];
                    a0 += v.x * rc[4 * kb + 0];
                    a1 += v.y * rc[4 * kb + 1];
                    a2 += v.z * rc[4 * kb + 2];
                    a3 += v.w * rc[4 * kb + 3];
                }
                Pz[kh * 516 + zc] = (a0 + a1) + (a2 + a3);
            }
            // P1b: prior-mean partial (threads 768..1023)
            if (t >= 768) {
                const float4* m4 = (const float4*)&m_lds[pq * 16];
                float p0 = 0.f, p1 = 0.f, p2 = 0.f, p3 = 0.f;
#pragma unroll
                for (int kb = 0; kb < 4; ++kb) {
                    const float4 v = m4[kb];
                    p0 += v.x * wf[4 * kb + 0];
                    p1 += v.y * wf[4 * kb + 1];
                    p2 += v.z * wf[4 * kb + 2];
                    p3 += v.w * wf[4 * kb + 3];
                }
                Pf[pq * 68 + pc] = (p0 + p1) + (p2 + p3);
            }
            __syncthreads();  // B1

            // P2: roles
            if (t < 128) {
                const float* az_ = &azs[si * 512];
                const float zi = Pz[t]       + Pz[516 + t]       + az_[t]       + bl0;
                const float zf = Pz[t + 128] + Pz[516 + t + 128] + az_[t + 128] + bl1;
                const float zg = Pz[t + 256] + Pz[516 + t + 256] + az_[t + 256] + bl2;
                const float zo = Pz[t + 384] + Pz[516 + t + 384] + az_[t + 384] + bl3;
                cst = sigmoidf(zf) * cst + sigmoidf(zi) * tanhf(zg);
                const float h = sigmoidf(zo) * tanhf(cst);
                h_lds[t] = h;
                hch[si * 132 + t] = h;
            } else if (t < 192) {
                const int c = t - 128;
                const float pm = Pf[c] + Pf[68 + c] + Pf[136 + c] + Pf[204 + c] + bfmr;
                m_lds[c] = pm;
                prmch[si * 68 + c] = pm;
            }
            __syncthreads();  // B2
        }

        // ---- chunk phase: heads (2 jobs) + prior-scale (1 job) per thread ----
        {
            float qA0 = 0.f, qA1 = 0.f, qA2 = 0.f, qA3 = 0.f;
            float qB0 = 0.f, qB1 = 0.f, qB2 = 0.f, qB3 = 0.f;
            const float* hA = &hch[hs2 * 132];
            const float* hB = &hch[(hs2 + 8) * 132];
#pragma unroll 4
            for (int kb = 0; kb < 32; ++kb) {
                const float w0 = Wcol[(4 * kb + 0) * 64];
                const float w1 = Wcol[(4 * kb + 1) * 64];
                const float w2 = Wcol[(4 * kb + 2) * 64];
                const float w3 = Wcol[(4 * kb + 3) * 64];
                const float4 a = *(const float4*)&hA[4 * kb];
                const float4 bv = *(const float4*)&hB[4 * kb];
                qA0 += a.x * w0;  qA1 += a.y * w1;  qA2 += a.z * w2;  qA3 += a.w * w3;
                qB0 += bv.x * w0; qB1 += bv.y * w1; qB2 += bv.z * w2; qB3 += bv.w * w3;
            }
            const float qA = (qA0 + qA1) + (qA2 + qA3) + hbias;
            const float qB = (qB0 + qB1) + (qB2 + qB3) + hbias;
            if (hc < 64) {
                qch[hs2 * 132 + hc] = qA;
                qch[(hs2 + 8) * 132 + hc] = qB;
                qrow[(size_t)(t0 + hs2) * SS + hc] = qA;
                qrow[(size_t)(t0 + hs2 + 8) * SS + hc] = qB;
            } else {
                qch[hs2 * 132 + hc] = softplusf(qA);
                qch[(hs2 + 8) * 132 + hc] = softplusf(qB);
            }

            // prior scale for (ss, pc): uses m_{ts-1}
            const float* m_in = (ss == 0) ? m0ch : &prmch[(ss - 1) * 68];
            float s0 = 0.f, s1 = 0.f, s2 = 0.f, s3 = 0.f;
#pragma unroll 4
            for (int kb = 0; kb < 16; ++kb) {
                const float w0 = Wfs[(4 * kb + 0) * 64 + pc];
                const float w1 = Wfs[(4 * kb + 1) * 64 + pc];
                const float w2 = Wfs[(4 * kb + 2) * 64 + pc];
                const float w3 = Wfs[(4 * kb + 3) * 64 + pc];
                const float4 mv = *(const float4*)&m_in[4 * kb];
                s0 += mv.x * w0; s1 += mv.y * w1; s2 += mv.z * w2; s3 += mv.w * w3;
            }
            sqch[ss * 68 + pc] = softplusf((s0 + s1) + (s2 + s3) + bfsr);
        }
        __syncthreads();  // C: qch/sqch ready

        // ---- KL for (ss, pc) ----
        {
            const float qm = qch[ss * 132 + pc];
            const float sp = qch[ss * 132 + 64 + pc];
            const float pm = prmch[ss * 68 + pc];
            const float sq = sqch[ss * 68 + pc];
            const float d = qm - pm;
            acckl += logf(sq) - logf(sp) + (sp * sp + d * d) / (2.f * sq * sq) - 0.5f;
        }
        // no barrier needed: next writes to prmch/qch/azs are all behind B1/B2
    }

    // ---- reduce KL: wave shuffle -> 16 partials -> atomic ----
    for (int off = 32; off > 0; off >>= 1) acckl += __shfl_down(acckl, off, 64);
    if ((t & 63) == 0) wred[t >> 6] = acckl;
    __syncthreads();
    if (t == 0) {
        float s = 0.f;
#pragma unroll
        for (int w = 0; w < 16; ++w) s += wred[w];
        atomicAdd(acc_out, (double)s * (1.0 / ((double)BB * (double)TT)));
    }
}

// ---------------- Kernel C2: generator heads + reconstruction -----------------
// 128 threads: thread t owns Wg_m[:,t] and Wg_s[:,t] (64+64 regs). 128 pos/block.
__global__ __launch_bounds__(128) void kC2(const float* __restrict__ obs,
                                           const float* __restrict__ qpm,
                                           const float* __restrict__ Wgm,
                                           const float* __restrict__ bgm,
                                           const float* __restrict__ Wgs,
                                           const float* __restrict__ bgs,
                                           double* __restrict__ acc_out) {
    __shared__ float red[128];
    const int t = threadIdx.x;
    float wgm[64], wgs[64];
#pragma unroll
    for (int k = 0; k < 64; ++k) {
        wgm[k] = Wgm[k * 128 + t];
        wgs[k] = Wgs[k * 128 + t];
    }
    const float bm = bgm[t];
    const float bs = bgs[t];

    float accr = 0.f;
    const size_t p0 = (size_t)blockIdx.x * 128;
    for (int i = 0; i < 128; ++i) {
        const size_t p = p0 + i;
        const float4* m4 = (const float4*)(qpm + p * 64);
        float m0 = 0.f, m1 = 0.f, m2 = 0.f, m3 = 0.f;
        float s0 = 0.f, s1 = 0.f, s2 = 0.f, s3 = 0.f;
#pragma unroll
        for (int kb = 0; kb < 16; ++kb) {
            const float4 v = m4[kb];
            m0 += v.x * wgm[kb * 4 + 0];
            m1 += v.y * wgm[kb * 4 + 1];
            m2 += v.z * wgm[kb * 4 + 2];
            m3 += v.w * wgm[kb * 4 + 3];
            s0 += v.x * wgs[kb * 4 + 0];
            s1 += v.y * wgs[kb * 4 + 1];
            s2 += v.z * wgs[kb * 4 + 2];
            s3 += v.w * wgs[kb * 4 + 3];
        }
        const float om = bm + ((m0 + m1) + (m2 + m3));
        const float os = softplusf(bs + ((s0 + s1) + (s2 + s3)));
        const float x = obs[p * 128 + t];
        const float d = (x - om) / os;
        accr += 0.5f * d * d + logf(os) + 0.5f * LOG2PI_F;
    }
    red[t] = accr;
    __syncthreads();
    for (int s = 64; s > 0; s >>= 1) {
        if (t < s) red[t] += red[t + s];
        __syncthreads();
    }
    if (t == 0) atomicAdd(acc_out, (double)red[0] * (1.0 / (double)BB));
}

extern "C" void kernel_launch(void* const* d_in, const int* in_sizes, int n_in,
                              void* d_out, int out_size, void* d_ws, size_t ws_size,
                              hipStream_t stream) {
    (void)in_sizes; (void)n_in; (void)out_size; (void)ws_size;

    const float* obs = (const float*)d_in[0];
    const float* im  = (const float*)d_in[1];
    // d_in[2] initial_scale: unused by the reference forward
    const float* Wfm = (const float*)d_in[3];
    const float* bfm = (const float*)d_in[4];
    const float* Wfs = (const float*)d_in[5];
    const float* bfs = (const float*)d_in[6];
    const float* Wgm = (const float*)d_in[7];
    const float* bgm = (const float*)d_in[8];
    const float* Wgs = (const float*)d_in[9];
    const float* bgs = (const float*)d_in[10];
    const float* K   = (const float*)d_in[11];
    const float* Rw  = (const float*)d_in[12];
    const float* bl  = (const float*)d_in[13];
    const float* Wrm = (const float*)d_in[14];
    const float* brm = (const float*)d_in[15];
    const float* Wrs = (const float*)d_in[16];
    const float* brs = (const float*)d_in[17];

    double* acc = (double*)((char*)d_ws + ACC_OFF);
    float* qpm  = (float*)((char*)d_ws + QPM_OFF);

    zero_acc_kernel<<<1, 1, 0, stream>>>(acc);
    kFused<<<BB, 1024, 0, stream>>>(obs, K, bl, Rw, Wfm, bfm, Wfs, bfs, im,
                                    Wrm, brm, Wrs, brs, qpm, acc);
    kC2<<<(BB * TT) / 128, 128, 0, stream>>>(obs, qpm, Wgm, bgm, Wgs, bgs, acc);
    finalize_kernel<<<1, 1, 0, stream>>>(acc, (float*)d_out);
}